// Round 15
// baseline (181.270 us; speedup 1.0000x reference)
//
#include <hip/hip_runtime.h>
#include <math.h>

#define H 8
#define NS 512
#define D 64

typedef __bf16 bf16x8 __attribute__((ext_vector_type(8)));
typedef _Float16 f16x8 __attribute__((ext_vector_type(8)));
typedef float f32x4 __attribute__((ext_vector_type(4)));
typedef short s16x8 __attribute__((ext_vector_type(8)));
typedef short s16x4 __attribute__((ext_vector_type(4)));

#define CS2 ((1e-3f/512.f)/(8.f+1e-6f))
#define LOG2E 1.4426950408889634

static __device__ __forceinline__ f32x4 mfma16(bf16x8 a, bf16x8 b, f32x4 c){
  return __builtin_amdgcn_mfma_f32_16x16x32_bf16(a,b,c,0,0,0);
}
static __device__ __forceinline__ f32x4 mfma16h(f16x8 a, f16x8 b, f32x4 c){
  return __builtin_amdgcn_mfma_f32_16x16x32_f16(a,b,c,0,0,0);
}
static __device__ __forceinline__ float b2f(unsigned short s){
  union { unsigned u; float f; } v; v.u = ((unsigned)s)<<16; return v.f;
}
static __device__ __forceinline__ unsigned short f2b(float f){
  union { float f; unsigned u; } v; v.f = f;
  unsigned r = v.u + 0x7FFFu + ((v.u>>16)&1u);
  return (unsigned short)(r>>16);
}
static __device__ __forceinline__ unsigned short f2h(float f){
  union { _Float16 h; unsigned short s; } cv; cv.h = (_Float16)f; return cv.s;
}
static __device__ __forceinline__ float h2f(unsigned short s){
  union { _Float16 h; unsigned short s; } cv; cv.s = s; return (float)cv.h;
}
static __device__ __forceinline__ float wred64(float v){
  #pragma unroll
  for(int m=32; m>0; m>>=1) v += __shfl_xor(v, m, 64);
  return v;
}

// ---- workspace layout (float element offsets) ----
constexpr size_t OFF_FQB = 6291456;                 // 8192x512 bf16
constexpr size_t OFF_FKB = 8388608;
constexpr size_t OFF_FVB = 10485760;
constexpr size_t OFF_FVT = 12582912;                // [128][64][512] fp16 (m-interleaved per 32-chunk)
constexpr size_t OFF_WT  = 14680064;                // 512x512 bf16 (WinT)
constexpr size_t OFF_WOH = 14811136;                // 512x512 fp16 WoutT hi
constexpr size_t OFF_WOL = 14942208;                // 512x512 fp16 WoutT lo
constexpr size_t OFF_OHH = 15073280;                // 8192x512 fp16 oh
constexpr size_t OFF_ARR = 19267584;                // arrays x 65536 f32
constexpr size_t OFF_SMK = OFF_ARR + 9*65536;
constexpr size_t OFF_COEF= OFF_SMK + 128;
constexpr size_t OFF_DBL = OFF_COEF + 32;           // 8B aligned (even)
constexpr size_t NDBL    = 72 + 1024;               // headsum[8][9], featd[8][128]

// ---------------- pre: W_in T bf16 (blocks<64, block0 zeroes dbl) + W_out T fp16 hi/lo ----------------
__global__ __launch_bounds__(256) void k_pre(const float* __restrict__ Win, const float* __restrict__ Wout,
    unsigned short* __restrict__ WT,
    unsigned short* __restrict__ WTh, unsigned short* __restrict__ WTl,
    double* __restrict__ dbl){
  int bx = blockIdx.x; int t = threadIdx.x;
  __shared__ float tile[64][65];
  if(bx < 64){
    int kt = bx>>3, nt = bx&7;
    if(bx==0){
      for(int i=t;i<(int)NDBL;i+=256) dbl[i]=0.0;
    }
    #pragma unroll
    for(int i=0;i<4;i++){
      int row = (t>>4) + i*16; int col = (t&15)*4;
      float4 vv = *(const float4*)(Win + (size_t)(kt*64+row)*512 + nt*64 + col);
      tile[row][col]=vv.x; tile[row][col+1]=vv.y; tile[row][col+2]=vv.z; tile[row][col+3]=vv.w;
    }
    __syncthreads();
    #pragma unroll
    for(int i=0;i<4;i++){
      int n = (t>>4) + i*16; int ck = (t&15)*4;
      s16x4 o;
      #pragma unroll
      for(int j=0;j<4;j++) o[j] = (short)f2b(tile[ck+j][n]);
      *(s16x4*)(WT + (size_t)(nt*64+n)*512 + kt*64 + ck) = o;
    }
  } else {
    int bb = bx - 64; int kt = bb>>3, nt = bb&7;
    #pragma unroll
    for(int i=0;i<4;i++){
      int row = (t>>4) + i*16; int col = (t&15)*4;
      float4 vv = *(const float4*)(Wout + (size_t)(kt*64+row)*512 + nt*64 + col);
      tile[row][col]=vv.x; tile[row][col+1]=vv.y; tile[row][col+2]=vv.z; tile[row][col+3]=vv.w;
    }
    __syncthreads();
    #pragma unroll
    for(int i=0;i<4;i++){
      int n = (t>>4) + i*16; int ck = (t&15)*4;
      s16x4 oh_, ol_;
      #pragma unroll
      for(int j=0;j<4;j++){
        float x = tile[ck+j][n];
        unsigned short hi = f2h(x);
        oh_[j] = (short)hi;
        ol_[j] = (short)f2h(x - h2f(hi));
      }
      *(s16x4*)(WTh + (size_t)(nt*64+n)*512 + kt*64 + ck) = oh_;
      *(s16x4*)(WTl + (size_t)(nt*64+n)*512 + kt*64 + ck) = ol_;
    }
  }
}

// ---------------- fused LN + proj GEMM bf16 MFMA, XCD-chunked ----------------
__global__ __launch_bounds__(256) void k_mm1(const float* __restrict__ q,
    const float* __restrict__ k, const float* __restrict__ v,
    const float* __restrict__ g, const float* __restrict__ b,
    const unsigned short* __restrict__ WT,
    unsigned short* __restrict__ fqb, unsigned short* __restrict__ fkb,
    unsigned short* __restrict__ fvb){
  __shared__ __align__(16) unsigned short As[128*64];
  __shared__ __align__(16) unsigned short Bs[128*64];
  __shared__ float muS[128], rsS[128];
  __shared__ float gS[512], bS[512];
  int t = threadIdx.x; int w = t>>6; int l = t&63; int g2 = l>>4, lc = l&15;
  int bid = blockIdx.x;
  int work = (bid&7)*96 + (bid>>3);        // 768 blocks, 96 per XCD chunk
  int Rb = (work>>2)*128, cb = (work&3)*128;
  int tsel = Rb>>13;
  const float* src = (tsel==0)?q:((tsel==1)?k:v);
  int r0 = Rb & 8191;
  unsigned short* dst = (tsel==0)?fqb:((tsel==1)?fkb:fvb);
  int wr = (w>>1)*64, wc = (w&1)*64;
  for(int i=t;i<512;i+=256){ gS[i]=g[i]; bS[i]=b[i]; }
  // phase 1: LN stats, 2 threads per row
  {
    int r = t>>1, p = t&1;
    const float4* rp = (const float4*)(src + (size_t)(r0+r)*512) + p*64;
    float s=0.f, ss=0.f;
    #pragma unroll 8
    for(int i=0;i<64;i++){
      float4 x = rp[i];
      s  += x.x+x.y+x.z+x.w;
      ss += x.x*x.x+x.y*x.y+x.z*x.z+x.w*x.w;
    }
    s += __shfl_xor(s,1,64); ss += __shfl_xor(ss,1,64);
    if(p==0){
      float mu = s*(1.f/512.f);
      float var = ss*(1.f/512.f) - mu*mu;
      muS[r] = mu; rsS[r] = rsqrtf(var + 1e-5f);
    }
  }
  f32x4 acc[4][4];
  #pragma unroll
  for(int i=0;i<4;i++)
    #pragma unroll
    for(int j=0;j<4;j++) acc[i][j] = (f32x4){0.f,0.f,0.f,0.f};
  __syncthreads();
  for(int k0=0; k0<512; k0+=64){
    if(k0) __syncthreads();
    // A tile: re-read 128x64 fp32 (L2-hot), apply LN, bf16 -> swizzled LDS
    #pragma unroll
    for(int i=0;i<4;i++){
      int c = t + i*256; int row = c>>3, k8 = c&7;
      const float* ap = src + (size_t)(r0+row)*512 + k0 + k8*8;
      float4 x0 = *(const float4*)ap;
      float4 x1 = *(const float4*)(ap+4);
      float mu = muS[row], rs = rsS[row];
      int cg = k0 + k8*8;
      s16x8 o;
      o[0]=(short)f2b((x0.x-mu)*rs*gS[cg+0]+bS[cg+0]);
      o[1]=(short)f2b((x0.y-mu)*rs*gS[cg+1]+bS[cg+1]);
      o[2]=(short)f2b((x0.z-mu)*rs*gS[cg+2]+bS[cg+2]);
      o[3]=(short)f2b((x0.w-mu)*rs*gS[cg+3]+bS[cg+3]);
      o[4]=(short)f2b((x1.x-mu)*rs*gS[cg+4]+bS[cg+4]);
      o[5]=(short)f2b((x1.y-mu)*rs*gS[cg+5]+bS[cg+5]);
      o[6]=(short)f2b((x1.z-mu)*rs*gS[cg+6]+bS[cg+6]);
      o[7]=(short)f2b((x1.w-mu)*rs*gS[cg+7]+bS[cg+7]);
      *(s16x8*)((char*)As + row*128 + ((k8*16) ^ ((row&7)<<4))) = o;
      s16x8 vb = *(const s16x8*)(WT + (size_t)(cb+row)*512 + k0 + k8*8);
      *(s16x8*)((char*)Bs + row*128 + ((k8*16) ^ ((row&7)<<4))) = vb;
    }
    __syncthreads();
    #pragma unroll
    for(int ks=0; ks<2; ks++){
      bf16x8 ar[4], br[4];
      #pragma unroll
      for(int rt=0; rt<4; rt++){
        int row = wr + rt*16 + lc;
        ar[rt] = *(const bf16x8*)((const char*)As + row*128 + (((ks*4+g2)*16) ^ ((row&7)<<4)));
      }
      #pragma unroll
      for(int ct=0; ct<4; ct++){
        int row = wc + ct*16 + lc;
        br[ct] = *(const bf16x8*)((const char*)Bs + row*128 + (((ks*4+g2)*16) ^ ((row&7)<<4)));
      }
      #pragma unroll
      for(int rt=0; rt<4; rt++)
        #pragma unroll
        for(int ct=0; ct<4; ct++)
          acc[rt][ct] = mfma16(ar[rt], br[ct], acc[rt][ct]);
    }
  }
  #pragma unroll
  for(int rt=0; rt<4; rt++){
    #pragma unroll
    for(int r=0; r<4; r++){
      int rr = r0 + wr + rt*16 + g2*4 + r;
      #pragma unroll
      for(int ct=0; ct<4; ct++){
        int c = cb + wc + ct*16 + lc;
        dst[(size_t)rr*512 + c] = f2b(acc[rt][ct][r]);
      }
    }
  }
}

// ---------------- fused mid: per-hq stats (blocks<128) + fv transpose->fp16 (512 blocks) ----------------
__global__ __launch_bounds__(512) void k_mid(const unsigned short* __restrict__ fqb,
    const unsigned short* __restrict__ fkb, const unsigned short* __restrict__ fvb,
    float* __restrict__ smk, double* featd,
    float* __restrict__ ri1, float* __restrict__ mq, float* __restrict__ qdm,
    float* __restrict__ ri2, float* __restrict__ sk,
    unsigned short* __restrict__ fvT){
  int bx = blockIdx.x; int t = threadIdx.x;
  if(bx < 128){
    int hq = bx; int h = hq>>4, q = hq&15;
    __shared__ float cq[8][64], ck[8][64], mkS[64];
    __shared__ float smkS;
    {
      int d = t&63; int g = t>>6;  // 8 n-groups
      float aq=0.f, ak=0.f;
      for(int n=g; n<512; n+=8){
        size_t base = (size_t)(q*512+n)*512 + h*64 + d;
        aq += b2f(fqb[base]);
        ak += b2f(fkb[base]);
      }
      cq[g][d]=aq; ck[g][d]=ak;
    }
    __syncthreads();
    if(t<64){
      float sq=0.f, sk2=0.f;
      #pragma unroll
      for(int i=0;i<8;i++){ sq+=cq[i][t]; sk2+=ck[i][t]; }
      atomicAdd(&featd[h*128+t], (double)sq);
      atomicAdd(&featd[h*128+64+t], (double)sk2);
      float mk = sk2*(1.f/512.f);
      mkS[t]=mk;
      float s = wred64(mk);
      if(t==0){ smk[hq]=s; smkS=s; }
    }
    __syncthreads();
    {
      int n = t;
      float smkv = smkS;
      const unsigned short* fr = fqb + (size_t)(q*512+n)*512 + h*64;
      const unsigned short* kr = fkb + (size_t)(q*512+n)*512 + h*64;
      float sq=0.f, ssq=0.f, dq=0.f, sks=0.f, ssk=0.f;
      #pragma unroll
      for(int j=0;j<8;j++){
        s16x8 vq = *(const s16x8*)(fr + j*8);
        s16x8 vk = *(const s16x8*)(kr + j*8);
        #pragma unroll
        for(int e=0;e<8;e++){
          float a = b2f((unsigned short)vq[e]);
          float c = b2f((unsigned short)vk[e]);
          sq += a; ssq += a*a; dq += a*mkS[j*8+e];
          sks += c; ssk += c*c;
        }
      }
      int idx = hq*512 + n;
      float nq = sqrtf(ssq);
      ri1[idx]  = 1.f/(nq+1e-6f);
      mq[idx]   = sq*(1.f/64.f);
      qdm[idx]  = dq;
      float nk = sqrtf(ssk);
      ri2[idx]  = 1.f/(nk+1e-6f);
      sk[idx]   = sks - smkv;
    }
    return;
  }
  {
    int bb = bx - 128; int hq = bb>>2, nc = bb&3;
    int h = hq>>4, q = hq&15; int n0 = nc*128;
    __shared__ float tile[128][65];
    #pragma unroll
    for(int i=0;i<2;i++){
      int c = t + i*512; int row = c>>3, k8 = c&7;
      s16x8 v = *(const s16x8*)(fvb + (size_t)(q*512 + n0 + row)*512 + h*64 + k8*8);
      #pragma unroll
      for(int j=0;j<8;j++) tile[row][k8*8+j] = b2f((unsigned short)v[j]);
    }
    __syncthreads();
    #pragma unroll
    for(int i=0;i<2;i++){
      int c = t + i*512; int d = c>>4, n8 = c&15;
      s16x8 o;
      #pragma unroll
      for(int j=0;j<8;j++){
        int p = n8*8+j;
        int pl = p & 31;
        int src = (p & ~31) | (16*(pl&1) + (pl>>1));
        o[j] = (short)f2h(tile[src][d]);
      }
      *(s16x8*)(fvT + (size_t)(hq*64 + d)*512 + n0 + n8*8) = o;
    }
  }
}

// ---------------- component sums pass (MFMA QK), 128 q-rows / 512 threads, XCD-swizzled ----------------
__global__ __launch_bounds__(512) void k_comp(const unsigned short* __restrict__ fqb,
    const unsigned short* __restrict__ fkb,
    const float* __restrict__ ri1,
    const float* __restrict__ mq, const float* __restrict__ qdm,
    const float* __restrict__ ri2,
    const float* __restrict__ skp,
    float* __restrict__ mxcg, float* __restrict__ mxvg, double* headsum){
  int bid = blockIdx.x;
  int bx = (bid&7)*64 + (bid>>3);          // XCD swizzle: 4 row-tiles of an hq share an XCD's L2
  int hq = bx>>2; int rt = bx&3;
  int h = hq>>4, q = hq&15; int n0 = rt*128;
  __shared__ __align__(16) unsigned short Qs[128*64];
  __shared__ __align__(16) unsigned short Ks[128*64];
  __shared__ float ri2f[512], skf[512];
  __shared__ float red[8][9];
  int t = threadIdx.x; int w = t>>6; int l = t&63; int g = l>>4, lc = l&15;
  for(int i=t; i<512; i+=512){
    ri2f[i]=ri2[hq*NS+i]; skf[i]=skp[hq*NS+i];
  }
  #pragma unroll
  for(int i=0;i<2;i++){
    int c = t + i*512; int row = c>>3, k8 = c&7;
    s16x8 v = *(const s16x8*)(fqb + (size_t)(q*512 + n0 + row)*512 + h*64 + k8*8);
    *(s16x8*)((char*)Qs + row*128 + ((k8*16) ^ ((row&7)<<4))) = v;
  }
  float ri1r[4], mqr[4], qdmr[4];
  #pragma unroll
  for(int r=0;r<4;r++){
    int n = hq*NS + n0 + w*16 + g*4 + r;
    ri1r[r]=ri1[n]; mqr[r]=mq[n]; qdmr[r]=qdm[n];
  }
  __syncthreads();
  bf16x8 aq[2];
  #pragma unroll
  for(int ks=0;ks<2;ks++){
    int row = 16*w + lc;
    aq[ks] = *(const bf16x8*)((const char*)Qs + row*128 + (((ks*4+g)*16) ^ ((row&7)<<4)));
  }
  float p1=0,p3=0,p4=0;
  float rm_m[4]={0,0,0,0}, rm_c[4]={0,0,0,0}, rm_v[4]={0,0,0,0};
  float mxc[4]={-1e30f,-1e30f,-1e30f,-1e30f}, mxv[4]={-1e30f,-1e30f,-1e30f,-1e30f};
  for(int mc=0; mc<4; mc++){
    __syncthreads();
    #pragma unroll
    for(int i=0;i<2;i++){
      int c = t + i*512; int row = c>>3, k8 = c&7;
      s16x8 v = *(const s16x8*)(fkb + (size_t)(q*512 + mc*128 + row)*512 + h*64 + k8*8);
      *(s16x8*)((char*)Ks + row*128 + ((k8*16) ^ ((row&7)<<4))) = v;
    }
    __syncthreads();
    #pragma unroll 2
    for(int mt=0; mt<8; mt++){
      f32x4 dacc = (f32x4){0.f,0.f,0.f,0.f};
      #pragma unroll
      for(int ks=0;ks<2;ks++){
        int row = mt*16 + lc;
        bf16x8 bk = *(const bf16x8*)((const char*)Ks + row*128 + (((ks*4+g)*16) ^ ((row&7)<<4)));
        dacc = mfma16(aq[ks], bk, dacc);
      }
      int m = mc*128 + mt*16 + lc;
      float r2 = ri2f[m], sc = skf[m];
      #pragma unroll
      for(int r=0;r<4;r++){
        float dv = dacc[r];
        float cosv = fminf(fmaxf(dv*ri1r[r]*r2, -0.9f), 0.9f);
        float inner = (dv - qdmr[r]) - mqr[r]*sc;
        float marg = fmaxf(0.01f - cosv, 0.f);
        p1 += cosv*cosv; p3 += inner*inner; p4 += cosv*inner;
        rm_m[r]+=marg; rm_c[r]+=cosv; rm_v[r]+=inner;
        mxc[r]=fmaxf(mxc[r],cosv); mxv[r]=fmaxf(mxv[r],inner);
      }
    }
  }
  float p0 = rm_c[0]+rm_c[1]+rm_c[2]+rm_c[3];
  float p2 = rm_v[0]+rm_v[1]+rm_v[2]+rm_v[3];
  #pragma unroll
  for(int off=1; off<16; off<<=1){
    #pragma unroll
    for(int r=0;r<4;r++){
      rm_m[r]+=__shfl_xor(rm_m[r],off,64);
      rm_c[r]+=__shfl_xor(rm_c[r],off,64);
      rm_v[r]+=__shfl_xor(rm_v[r],off,64);
      mxc[r]=fmaxf(mxc[r],__shfl_xor(mxc[r],off,64));
      mxv[r]=fmaxf(mxv[r],__shfl_xor(mxv[r],off,64));
    }
  }
  float q0=0,q1=0,q2=0,q3=0;
  if(lc==0){
    #pragma unroll
    for(int r=0;r<4;r++){
      float vmv = rm_m[r]*(1.f/512.f);
      q0+=vmv; q1+=vmv*vmv; q2+=vmv*rm_c[r]; q3+=vmv*rm_v[r];
      int n = n0 + w*16 + g*4 + r;
      mxcg[hq*NS+n]=mxc[r]; mxvg[hq*NS+n]=mxv[r];
    }
  }
  float all9[9] = {p0,p1,p2,p3,p4,q0,q1,q2,q3};
  #pragma unroll
  for(int j=0;j<9;j++){
    float vv = wred64(all9[j]);
    if(l==0) red[w][j]=vv;
  }
  __syncthreads();
  if(t<9){
    double s = 0.0;
    #pragma unroll
    for(int i=0;i<8;i++) s += (double)red[i][t];
    atomicAdd(&headsum[h*9+t], s);
  }
}

// ---------------- finalize (512 threads, all heads parallel) ----------------
__global__ __launch_bounds__(512) void k_finalize(const double* headsum, const double* featd,
    const float* __restrict__ w1, const float* __restrict__ b1,
    const float* __restrict__ lng, const float* __restrict__ lnb,
    const float* __restrict__ w2, const float* __restrict__ b2,
    const float* __restrict__ w3, const float* __restrict__ b3,
    const float* __restrict__ wtemp, float* coef){
  __shared__ float fS[1024];
  __shared__ float x1[1024];
  __shared__ float x2[512];
  __shared__ float oS[8][3], whS[8][3];
  int t = threadIdx.x;
  fS[t]     = (float)(featd[t]     * (1.0/8192.0));
  fS[t+512] = (float)(featd[t+512] * (1.0/8192.0));
  __syncthreads();
  int hh = t>>6, j = t&63;
  {
    float a0 = b1[j], a1 = b1[j+64];
    #pragma unroll 8
    for(int i=0;i<128;i++){
      float f = fS[hh*128+i];
      a0 += f*w1[(size_t)i*128 + j];
      a1 += f*w1[(size_t)i*128 + j + 64];
    }
    float s = a0+a1, ss = a0*a0+a1*a1;
    s = wred64(s); ss = wred64(ss);
    float mu = s*(1.f/128.f), var = ss*(1.f/128.f)-mu*mu;
    float rstd = rsqrtf(var+1e-5f);
    x1[hh*128+j]    = fmaxf((a0-mu)*rstd*lng[j]+lnb[j], 0.f);
    x1[hh*128+j+64] = fmaxf((a1-mu)*rstd*lng[j+64]+lnb[j+64], 0.f);
  }
  __syncthreads();
  {
    float s2 = b2[j];
    #pragma unroll 8
    for(int i=0;i<128;i++) s2 += x1[hh*128+i]*w2[(size_t)i*64+j];
    x2[hh*64+j] = fmaxf(s2, 0.f);
  }
  __syncthreads();
  if(t < 24){
    int h3 = t/3, j3 = t-h3*3;
    float s3=0.f;
    #pragma unroll 8
    for(int i=0;i<64;i++) s3 += x2[h3*64+i]*w3[i*3+j3];
    oS[h3][j3] = s3 + b3[j3];
  }
  __syncthreads();
  if(t < 8){
    float o0=oS[t][0], o1=oS[t][1], o2=oS[t][2];
    float mx=fmaxf(o0,fmaxf(o1,o2));
    float e0=expf(o0-mx), e1=expf(o1-mx), e2=expf(o2-mx), se=e0+e1+e2;
    float l0=e0/se, l1=e1/se, l2=e2/se;
    float wt=fminf(fmaxf(wtemp[0],0.1f),2.0f);
    l0/=wt; l1/=wt; l2/=wt;
    mx=fmaxf(l0,fmaxf(l1,l2));
    e0=expf(l0-mx); e1=expf(l1-mx); e2=expf(l2-mx); se=e0+e1+e2;
    float u0=fminf(fmaxf(e0/se,0.05f),0.8f);
    float u1=fminf(fmaxf(e1/se,0.05f),0.8f);
    float u2=fminf(fmaxf(e2/se,0.05f),0.8f);
    float su=u0+u1+u2;
    whS[t][0]=u0/su; whS[t][1]=u1/su; whS[t][2]=u2/su;
  }
  __syncthreads();
  if(t==0){
    const double N = 33554432.0;
    const double CS2d = (double)CS2;
    double gs[9];
    for(int jj=0;jj<9;jj++){ double s=0; for(int h2=0;h2<8;h2++) s+=headsum[h2*9+jj]; gs[jj]=s; }
    auto sd = [&](double s, double ss)->double{
      double vv=(ss - s*s/N)/(N-1.0); return vv>0.0 ? sqrt(vv) : 0.0;
    };
    double std_cos = sd(gs[0],gs[1]);
    double std_cov = sd(CS2d*gs[2], CS2d*CS2d*gs[3]);
    double std_vm  = sd(512.0*gs[5], 512.0*gs[6]);
    double sdot=0.0, sdot2=0.0;
    double Af[8], Bf[8];
    for(int h2=0;h2<8;h2++){
      const double* hs = headsum + h2*9;
      double A = (double)whS[h2][0]/(std_cos+1e-6);
      double Bi = (double)whS[h2][1]/(std_cov+1e-6)*0.5*CS2d;
      double C = (double)whS[h2][2]/(std_vm +1e-6)*0.5;
      sdot  += A*hs[0] + Bi*hs[2] + C*512.0*hs[5];
      sdot2 += A*A*hs[1] + Bi*Bi*hs[3] + C*C*512.0*hs[6]
             + 2.0*A*Bi*hs[4] + 2.0*A*C*hs[7] + 2.0*Bi*C*hs[8];
      Af[h2]=A; Bf[h2]=Bi;
    }
    double dstd = sd(sdot, sdot2);
    double temp = dstd < 1e-4 ? 0.1 : (dstd < 0.01 ? 0.3 : 0.5 + dstd);
    temp = fmin(fmax(temp, 0.1), 3.0);
    for(int h2=0;h2<8;h2++){
      coef[h2]   = (float)(Af[h2]/temp*LOG2E);
      coef[8+h2] = (float)(Bf[h2]/temp*LOG2E);
    }
    coef[16] = (float)temp;
  }
}

// ---------------- flash softmax + PV (fp16 P/V), 128 q-rows / 512 threads, XCD-swizzled ----------------
__global__ __launch_bounds__(512) void k_flash(const unsigned short* __restrict__ fqb,
    const unsigned short* __restrict__ fkb, const unsigned short* __restrict__ fvT,
    const float* __restrict__ ri1, const float* __restrict__ mq,
    const float* __restrict__ qdm, const float* __restrict__ ri2,
    const float* __restrict__ skp,
    const float* __restrict__ mxcg, const float* __restrict__ mxvg,
    const float* __restrict__ coef,
    unsigned short* __restrict__ ohh){
  int bid = blockIdx.x;
  int bx = (bid&7)*64 + (bid>>3);          // XCD swizzle
  int hq = bx>>2; int rt = bx&3;
  int h = hq>>4, q = hq&15; int n0 = rt*128;
  __shared__ __align__(16) unsigned short Qs[128*64];  // reused as P after aq extraction
  __shared__ __align__(16) unsigned short Ks[128*64];
  __shared__ __align__(16) unsigned short Vt[64*128];
  __shared__ float ri2f[512], skf[512];
  int t = threadIdx.x; int w = t>>6; int l = t&63; int g = l>>4, lc = l&15;
  for(int i=t; i<512; i+=512){ ri2f[i]=ri2[hq*NS+i]; skf[i]=skp[hq*NS+i]; }
  #pragma unroll
  for(int i=0;i<2;i++){
    int c = t + i*512; int row = c>>3, k8 = c&7;
    s16x8 v = *(const s16x8*)(fqb + (size_t)(q*512 + n0 + row)*512 + h*64 + k8*8);
    *(s16x8*)((char*)Qs + row*128 + ((k8*16) ^ ((row&7)<<4))) = v;
  }
  float Ah = coef[h], Bh = coef[8+h];
  float loA = -0.9f*Ah, hiA = 0.9f*Ah;
  float ri1A[4], R1[4], R2[4];
  #pragma unroll
  for(int r=0;r<4;r++){
    int n = hq*NS + n0 + w*16 + g*4 + r;
    float Mr = Ah*mxcg[n] + Bh*mxvg[n];
    ri1A[r] = ri1[n]*Ah;
    R1[r] = fmaf(Bh, qdm[n], Mr);
    R2[r] = Bh*mq[n];
  }
  __syncthreads();
  bf16x8 aq[2];
  #pragma unroll
  for(int ks=0;ks<2;ks++){
    int row = 16*w + lc;
    aq[ks] = *(const bf16x8*)((const char*)Qs + row*128 + (((ks*4+g)*16) ^ ((row&7)<<4)));
  }
  f32x4 acc[4];
  #pragma unroll
  for(int dt=0;dt<4;dt++) acc[dt] = (f32x4){0.f,0.f,0.f,0.f};
  float lsum[4]={0.f,0.f,0.f,0.f};
  unsigned short* Pw = Qs + w*640;
  unsigned* Pu = (unsigned*)Pw;
  for(int mc=0; mc<4; mc++){
    __syncthreads();
    #pragma unroll
    for(int i=0;i<2;i++){
      int c = t + i*512; int row = c>>3, k8 = c&7;
      s16x8 v = *(const s16x8*)(fkb + (size_t)(q*512 + mc*128 + row)*512 + h*64 + k8*8);
      *(s16x8*)((char*)Ks + row*128 + ((k8*16) ^ ((row&7)<<4))) = v;
    }
    #pragma unroll
    for(int i=0;i<2;i++){
      int c = t + i*512; int d = c>>4, m8 = c&15;
      s16x8 v = *(const s16x8*)(fvT + (size_t)(hq*64 + d)*512 + mc*128 + m8*8);
      *(s16x8*)((char*)Vt + d*256 + ((m8*16) ^ ((d&7)<<4))) = v;
    }
    __syncthreads();
    #pragma unroll 1
    for(int mt2=0; mt2<4; mt2++){
      f32x4 d0 = (f32x4){0.f,0.f,0.f,0.f};
      f32x4 d1 = (f32x4){0.f,0.f,0.f,0.f};
      #pragma unroll
      for(int ks=0;ks<2;ks++){
        int row0 = (mt2*2)*16 + lc;
        bf16x8 bk0 = *(const bf16x8*)((const char*)Ks + row0*128 + (((ks*4+g)*16) ^ ((row0&7)<<4)));
        d0 = mfma16(aq[ks], bk0, d0);
        int row1 = (mt2*2+1)*16 + lc;
        bf16x8 bk1 = *(const bf16x8*)((const char*)Ks + row1*128 + (((ks*4+g)*16) ^ ((row1&7)<<4)));
        d1 = mfma16(aq[ks], bk1, d1);
      }
      int m0 = mc*128 + mt2*32 + lc;
      float r20 = ri2f[m0],    sc0 = skf[m0];
      float r21 = ri2f[m0+16], sc1 = skf[m0+16];
      #pragma unroll
      for(int r=0;r<4;r++){
        float dv0 = d0[r], dv1 = d1[r];
        float cl0 = fminf(fmaxf(dv0*ri1A[r]*r20, loA), hiA);
        float cl1 = fminf(fmaxf(dv1*ri1A[r]*r21, loA), hiA);
        float e0 = fmaf(-R2[r], sc0, fmaf(Bh, dv0, -R1[r]));
        float e1 = fmaf(-R2[r], sc1, fmaf(Bh, dv1, -R1[r]));
        float pe0 = __builtin_amdgcn_exp2f(cl0 + e0);
        float pe1 = __builtin_amdgcn_exp2f(cl1 + e1);
        lsum[r] += pe0 + pe1;
        auto ph = __builtin_amdgcn_cvt_pkrtz(pe0, pe1);
        unsigned pk; __builtin_memcpy(&pk, &ph, 4);
        Pu[(g*4+r)*20 + lc] = pk;
      }
      asm volatile("s_waitcnt lgkmcnt(0)" ::: "memory");
      f16x8 ap = *(const f16x8*)((const char*)Pw + lc*80 + g*16);
      #pragma unroll
      for(int dt=0;dt<4;dt++){
        int drow = dt*16 + lc;
        f16x8 bv = *(const f16x8*)((const char*)Vt + drow*256 + (((mt2*4+g)*16) ^ ((drow&7)<<4)));
        acc[dt] = mfma16h(ap, bv, acc[dt]);
      }
    }
  }
  #pragma unroll
  for(int off=1; off<16; off<<=1){
    #pragma unroll
    for(int r=0;r<4;r++) lsum[r] += __shfl_xor(lsum[r], off, 64);
  }
  #pragma unroll
  for(int r=0;r<4;r++){
    float inv = 1.f/lsum[r];
    int n = n0 + w*16 + g*4 + r;
    #pragma unroll
    for(int dt=0;dt<4;dt++){
      size_t idx = (size_t)(q*512 + n)*512 + h*64 + dt*16 + lc;
      ohh[idx] = f2h(acc[dt][r]*inv);
    }
  }
}

// ---------------- output GEMM: fp16 A x fp16 (Bh+Bl) 2-term MFMA + bias, XCD-chunked ----------------
__global__ __launch_bounds__(256) void k_gout2(const unsigned short* __restrict__ Ap,
    const unsigned short* __restrict__ Bhp, const unsigned short* __restrict__ Blp,
    const float* __restrict__ bias, float* __restrict__ Cout){
  __shared__ __align__(16) unsigned short As[128*64];
  __shared__ __align__(16) unsigned short BsH[128*64];
  __shared__ __align__(16) unsigned short BsL[128*64];
  int t = threadIdx.x; int w = t>>6; int l = t&63; int g = l>>4, lc = l&15;
  int bid = blockIdx.x;
  int work = (bid&7)*32 + (bid>>3);        // 256 blocks, 32 per XCD chunk
  int Rb = (work>>2)*128, cb = (work&3)*128;
  int wr = (w>>1)*64, wc = (w&1)*64;
  f32x4 acc[4][4];
  #pragma unroll
  for(int i=0;i<4;i++)
    #pragma unroll
    for(int j=0;j<4;j++) acc[i][j] = (f32x4){0.f,0.f,0.f,0.f};
  for(int k0=0; k0<512; k0+=64){
    __syncthreads();
    #pragma unroll
    for(int i=0;i<4;i++){
      int c = t + i*256; int row = c>>3, k8 = c&7;
      int sw = (k8*16) ^ ((row&7)<<4);
      *(s16x8*)((char*)As  + row*128 + sw) = *(const s16x8*)(Ap  + (size_t)(Rb+row)*512 + k0 + k8*8);
      *(s16x8*)((char*)BsH + row*128 + sw) = *(const s16x8*)(Bhp + (size_t)(cb+row)*512 + k0 + k8*8);
      *(s16x8*)((char*)BsL + row*128 + sw) = *(const s16x8*)(Blp + (size_t)(cb+row)*512 + k0 + k8*8);
    }
    __syncthreads();
    #pragma unroll
    for(int ks=0; ks<2; ks++){
      f16x8 ar[4], brh[4], brl[4];
      #pragma unroll
      for(int rt=0; rt<4; rt++){
        int row = wr + rt*16 + lc;
        ar[rt] = *(const f16x8*)((const char*)As + row*128 + (((ks*4+g)*16) ^ ((row&7)<<4)));
      }
      #pragma unroll
      for(int ct=0; ct<4; ct++){
        int row = wc + ct*16 + lc;
        int off = row*128 + (((ks*4+g)*16) ^ ((row&7)<<4));
        brh[ct] = *(const f16x8*)((const char*)BsH + off);
        brl[ct] = *(const f16x8*)((const char*)BsL + off);
      }
      #pragma unroll
      for(int rt=0; rt<4; rt++)
        #pragma unroll
        for(int ct=0; ct<4; ct++){
          acc[rt][ct] = mfma16h(ar[rt], brh[ct], acc[rt][ct]);
          acc[rt][ct] = mfma16h(ar[rt], brl[ct], acc[rt][ct]);
        }
    }
  }
  #pragma unroll
  for(int rt=0; rt<4; rt++){
    #pragma unroll
    for(int r=0; r<4; r++){
      int R = Rb + wr + rt*16 + g*4 + r;
      #pragma unroll
      for(int ct=0; ct<4; ct++){
        int c = cb + wc + ct*16 + lc;
        Cout[(size_t)R*512 + c] = acc[rt][ct][r] + bias[c];
      }
    }
  }
}

extern "C" void kernel_launch(void* const* d_in, const int* in_sizes, int n_in,
                              void* d_out, int out_size, void* d_ws, size_t ws_size,
                              hipStream_t stream){
  const float* q    = (const float*)d_in[0];
  const float* k    = (const float*)d_in[1];
  const float* v    = (const float*)d_in[2];
  const float* ln1g = (const float*)d_in[3];
  const float* ln1b = (const float*)d_in[4];
  const float* Win  = (const float*)d_in[5];
  const float* w1   = (const float*)d_in[6];
  const float* b1   = (const float*)d_in[7];
  const float* lng  = (const float*)d_in[8];
  const float* lnb  = (const float*)d_in[9];
  const float* w2   = (const float*)d_in[10];
  const float* b2   = (const float*)d_in[11];
  const float* w3   = (const float*)d_in[12];
  const float* b3   = (const float*)d_in[13];
  const float* wtemp= (const float*)d_in[14];
  const float* Wout = (const float*)d_in[15];
  const float* bout = (const float*)d_in[16];

  float* w = (float*)d_ws;
  unsigned short* fqb = (unsigned short*)(w + OFF_FQB);
  unsigned short* fkb = (unsigned short*)(w + OFF_FKB);
  unsigned short* fvb = (unsigned short*)(w + OFF_FVB);
  unsigned short* fvT = (unsigned short*)(w + OFF_FVT);
  unsigned short* wtb = (unsigned short*)(w + OFF_WT);
  unsigned short* woh = (unsigned short*)(w + OFF_WOH);
  unsigned short* wol = (unsigned short*)(w + OFF_WOL);
  unsigned short* ohh = (unsigned short*)(w + OFF_OHH);
  float* ri1  = w + OFF_ARR + 0*65536;
  float* mq_  = w + OFF_ARR + 2*65536;
  float* qdm  = w + OFF_ARR + 3*65536;
  float* ri2  = w + OFF_ARR + 4*65536;
  float* sk_  = w + OFF_ARR + 6*65536;
  float* mxc  = w + OFF_ARR + 7*65536;
  float* mxv  = w + OFF_ARR + 8*65536;
  float* smk_ = w + OFF_SMK;
  float* coef = w + OFF_COEF;
  double* dbl = (double*)(w + OFF_DBL);
  double* headsum = dbl;
  double* featd   = dbl + 72;

  k_pre<<<128, 256, 0, stream>>>(Win, Wout, wtb, woh, wol, dbl);
  k_mm1<<<768, 256, 0, stream>>>(q, k, v, ln1g, ln1b, wtb, fqb, fkb, fvb);
  k_mid<<<640, 512, 0, stream>>>(fqb, fkb, fvb, smk_, featd, ri1, mq_, qdm, ri2, sk_, fvT);
  k_comp<<<512, 512, 0, stream>>>(fqb, fkb, ri1, mq_, qdm, ri2, sk_, mxc, mxv, headsum);
  k_finalize<<<1, 512, 0, stream>>>(headsum, featd, w1, b1, lng, lnb, w2, b2, w3, b3, wtemp, coef);
  k_flash<<<512, 512, 0, stream>>>(fqb, fkb, fvT, ri1, mq_, qdm, ri2, sk_, mxc, mxv, coef, ohh);
  k_gout2<<<256, 256, 0, stream>>>(ohh, woh, wol, bout, (float*)d_out);
}

// Round 16
// 143.226 us; speedup vs baseline: 1.2656x; 1.2656x over previous
//
#include <hip/hip_runtime.h>
#include <math.h>

#define H 8
#define NS 512
#define D 64

typedef __bf16 bf16x8 __attribute__((ext_vector_type(8)));
typedef _Float16 f16x8 __attribute__((ext_vector_type(8)));
typedef float f32x4 __attribute__((ext_vector_type(4)));
typedef short s16x8 __attribute__((ext_vector_type(8)));
typedef short s16x4 __attribute__((ext_vector_type(4)));

#define CS2 ((1e-3f/512.f)/(8.f+1e-6f))
#define LOG2E 1.4426950408889634

static __device__ __forceinline__ f32x4 mfma16(bf16x8 a, bf16x8 b, f32x4 c){
  return __builtin_amdgcn_mfma_f32_16x16x32_bf16(a,b,c,0,0,0);
}
static __device__ __forceinline__ f32x4 mfma16h(f16x8 a, f16x8 b, f32x4 c){
  return __builtin_amdgcn_mfma_f32_16x16x32_f16(a,b,c,0,0,0);
}
static __device__ __forceinline__ float b2f(unsigned short s){
  union { unsigned u; float f; } v; v.u = ((unsigned)s)<<16; return v.f;
}
static __device__ __forceinline__ unsigned short f2b(float f){
  union { float f; unsigned u; } v; v.f = f;
  unsigned r = v.u + 0x7FFFu + ((v.u>>16)&1u);
  return (unsigned short)(r>>16);
}
static __device__ __forceinline__ unsigned short f2h(float f){
  union { _Float16 h; unsigned short s; } cv; cv.h = (_Float16)f; return cv.s;
}
static __device__ __forceinline__ float h2f(unsigned short s){
  union { _Float16 h; unsigned short s; } cv; cv.s = s; return (float)cv.h;
}
static __device__ __forceinline__ float wred64(float v){
  #pragma unroll
  for(int m=32; m>0; m>>=1) v += __shfl_xor(v, m, 64);
  return v;
}

// ---- workspace layout (float element offsets) ----
constexpr size_t OFF_XNB = 0;                       // 24576x512 bf16
constexpr size_t OFF_FQB = 6291456;                 // 8192x512 bf16
constexpr size_t OFF_FKB = 8388608;
constexpr size_t OFF_FVB = 10485760;
constexpr size_t OFF_FVT = 12582912;                // [128][64][512] fp16 (m-interleaved per 32-chunk)
constexpr size_t OFF_WT  = 14680064;                // 512x512 bf16 (WinT)
constexpr size_t OFF_WOH = 14811136;                // 512x512 fp16 WoutT hi
constexpr size_t OFF_WOL = 14942208;                // 512x512 fp16 WoutT lo
constexpr size_t OFF_OHH = 15073280;                // 8192x512 fp16 oh
constexpr size_t OFF_ARR = 19267584;                // arrays x 65536 f32
constexpr size_t OFF_SMK = OFF_ARR + 9*65536;
constexpr size_t OFF_COEF= OFF_SMK + 128;
constexpr size_t OFF_DBL = OFF_COEF + 32;           // 8B aligned (even)
constexpr size_t NDBL    = 72 + 1024;               // headsum[8][9], featd[8][128]

// ---------------- fused pre: LayerNorm (blocks<6144) + W_in T (64) + W_out T fp16 hi/lo (64) ----------------
__global__ __launch_bounds__(256) void k_pre(const float* __restrict__ q,
    const float* __restrict__ k, const float* __restrict__ v,
    const float* __restrict__ g, const float* __restrict__ b,
    const float* __restrict__ Win, const float* __restrict__ Wout,
    unsigned short* __restrict__ xnb, unsigned short* __restrict__ WT,
    unsigned short* __restrict__ WTh, unsigned short* __restrict__ WTl,
    double* __restrict__ dbl){
  int bx = blockIdx.x; int t = threadIdx.x;
  if(bx < 6144){
    int row = bx*4 + (t>>6); int l = t & 63;
    const float* src = (row < 8192) ? q : ((row < 16384) ? k : v);
    int r = row & 8191;
    const float4* sp = (const float4*)(src + (size_t)r*512);
    float4 v1 = sp[l*2], v2 = sp[l*2+1];
    float s  = v1.x+v1.y+v1.z+v1.w + v2.x+v2.y+v2.z+v2.w;
    float ss = v1.x*v1.x+v1.y*v1.y+v1.z*v1.z+v1.w*v1.w
             + v2.x*v2.x+v2.y*v2.y+v2.z*v2.z+v2.w*v2.w;
    s = wred64(s); ss = wred64(ss);
    float mu = s*(1.f/512.f);
    float var = ss*(1.f/512.f) - mu*mu;
    float rstd = rsqrtf(var + 1e-5f);
    const float4* gp = (const float4*)g; const float4* bp = (const float4*)b;
    float4 g1 = gp[l*2], g2 = gp[l*2+1], b1 = bp[l*2], b2 = bp[l*2+1];
    s16x8 o;
    o[0]=(short)f2b((v1.x-mu)*rstd*g1.x+b1.x); o[1]=(short)f2b((v1.y-mu)*rstd*g1.y+b1.y);
    o[2]=(short)f2b((v1.z-mu)*rstd*g1.z+b1.z); o[3]=(short)f2b((v1.w-mu)*rstd*g1.w+b1.w);
    o[4]=(short)f2b((v2.x-mu)*rstd*g2.x+b2.x); o[5]=(short)f2b((v2.y-mu)*rstd*g2.y+b2.y);
    o[6]=(short)f2b((v2.z-mu)*rstd*g2.z+b2.z); o[7]=(short)f2b((v2.w-mu)*rstd*g2.w+b2.w);
    *(s16x8*)(xnb + (size_t)row*512 + l*8) = o;
    return;
  }
  __shared__ float tile[64][65];
  if(bx < 6208){
    int bb = bx - 6144; int kt = bb>>3, nt = bb&7;
    if(bb==0){
      for(int i=t;i<(int)NDBL;i+=256) dbl[i]=0.0;
    }
    #pragma unroll
    for(int i=0;i<4;i++){
      int row = (t>>4) + i*16; int col = (t&15)*4;
      float4 vv = *(const float4*)(Win + (size_t)(kt*64+row)*512 + nt*64 + col);
      tile[row][col]=vv.x; tile[row][col+1]=vv.y; tile[row][col+2]=vv.z; tile[row][col+3]=vv.w;
    }
    __syncthreads();
    #pragma unroll
    for(int i=0;i<4;i++){
      int n = (t>>4) + i*16; int ck = (t&15)*4;
      s16x4 o;
      #pragma unroll
      for(int j=0;j<4;j++) o[j] = (short)f2b(tile[ck+j][n]);
      *(s16x4*)(WT + (size_t)(nt*64+n)*512 + kt*64 + ck) = o;
    }
  } else {
    int bb = bx - 6208; int kt = bb>>3, nt = bb&7;
    #pragma unroll
    for(int i=0;i<4;i++){
      int row = (t>>4) + i*16; int col = (t&15)*4;
      float4 vv = *(const float4*)(Wout + (size_t)(kt*64+row)*512 + nt*64 + col);
      tile[row][col]=vv.x; tile[row][col+1]=vv.y; tile[row][col+2]=vv.z; tile[row][col+3]=vv.w;
    }
    __syncthreads();
    #pragma unroll
    for(int i=0;i<4;i++){
      int n = (t>>4) + i*16; int ck = (t&15)*4;
      s16x4 oh_, ol_;
      #pragma unroll
      for(int j=0;j<4;j++){
        float x = tile[ck+j][n];
        unsigned short hi = f2h(x);
        oh_[j] = (short)hi;
        ol_[j] = (short)f2h(x - h2f(hi));
      }
      *(s16x4*)(WTh + (size_t)(nt*64+n)*512 + kt*64 + ck) = oh_;
      *(s16x4*)(WTl + (size_t)(nt*64+n)*512 + kt*64 + ck) = ol_;
    }
  }
}

// ---------------- proj GEMM bf16 MFMA, XCD-chunked ----------------
__global__ __launch_bounds__(256) void k_mm1(const unsigned short* __restrict__ xnb,
    const unsigned short* __restrict__ WT,
    unsigned short* __restrict__ fqb, unsigned short* __restrict__ fkb,
    unsigned short* __restrict__ fvb){
  __shared__ __align__(16) unsigned short As[128*64];
  __shared__ __align__(16) unsigned short Bs[128*64];
  int t = threadIdx.x; int w = t>>6; int l = t&63; int g = l>>4, lc = l&15;
  int bid = blockIdx.x;
  int work = (bid&7)*96 + (bid>>3);        // 768 blocks, 96 per XCD chunk
  int Rb = (work>>2)*128, cb = (work&3)*128;
  int wr = (w>>1)*64, wc = (w&1)*64;
  f32x4 acc[4][4];
  #pragma unroll
  for(int i=0;i<4;i++)
    #pragma unroll
    for(int j=0;j<4;j++) acc[i][j] = (f32x4){0.f,0.f,0.f,0.f};
  for(int k0=0; k0<512; k0+=64){
    __syncthreads();
    #pragma unroll
    for(int i=0;i<4;i++){
      int c = t + i*256; int row = c>>3, k8 = c&7;
      s16x8 va = *(const s16x8*)(xnb + (size_t)(Rb+row)*512 + k0 + k8*8);
      *(s16x8*)((char*)As + row*128 + ((k8*16) ^ ((row&7)<<4))) = va;
      s16x8 vb = *(const s16x8*)(WT + (size_t)(cb+row)*512 + k0 + k8*8);
      *(s16x8*)((char*)Bs + row*128 + ((k8*16) ^ ((row&7)<<4))) = vb;
    }
    __syncthreads();
    #pragma unroll
    for(int ks=0; ks<2; ks++){
      bf16x8 ar[4], br[4];
      #pragma unroll
      for(int rt=0; rt<4; rt++){
        int row = wr + rt*16 + lc;
        ar[rt] = *(const bf16x8*)((const char*)As + row*128 + (((ks*4+g)*16) ^ ((row&7)<<4)));
      }
      #pragma unroll
      for(int ct=0; ct<4; ct++){
        int row = wc + ct*16 + lc;
        br[ct] = *(const bf16x8*)((const char*)Bs + row*128 + (((ks*4+g)*16) ^ ((row&7)<<4)));
      }
      #pragma unroll
      for(int rt=0; rt<4; rt++)
        #pragma unroll
        for(int ct=0; ct<4; ct++)
          acc[rt][ct] = mfma16(ar[rt], br[ct], acc[rt][ct]);
    }
  }
  #pragma unroll
  for(int rt=0; rt<4; rt++){
    #pragma unroll
    for(int r=0; r<4; r++){
      int R = Rb + wr + rt*16 + g*4 + r;
      int tsel = R>>13; int rr = R&8191;
      unsigned short* dst = (tsel==0)?fqb:((tsel==1)?fkb:fvb);
      #pragma unroll
      for(int ct=0; ct<4; ct++){
        int c = cb + wc + ct*16 + lc;
        dst[(size_t)rr*512 + c] = f2b(acc[rt][ct][r]);
      }
    }
  }
}

// ---------------- fused mid: per-hq stats (blocks<128) + fv transpose->fp16 (512 blocks) ----------------
__global__ __launch_bounds__(512) void k_mid(const unsigned short* __restrict__ fqb,
    const unsigned short* __restrict__ fkb, const unsigned short* __restrict__ fvb,
    float* __restrict__ smk, double* featd,
    float* __restrict__ ri1, float* __restrict__ mq, float* __restrict__ qdm,
    float* __restrict__ ri2, float* __restrict__ sk,
    unsigned short* __restrict__ fvT){
  int bx = blockIdx.x; int t = threadIdx.x;
  if(bx < 128){
    int hq = bx; int h = hq>>4, q = hq&15;
    __shared__ float cq[8][64], ck[8][64], mkS[64];
    __shared__ float smkS;
    {
      int d = t&63; int g = t>>6;  // 8 n-groups
      float aq=0.f, ak=0.f;
      for(int n=g; n<512; n+=8){
        size_t base = (size_t)(q*512+n)*512 + h*64 + d;
        aq += b2f(fqb[base]);
        ak += b2f(fkb[base]);
      }
      cq[g][d]=aq; ck[g][d]=ak;
    }
    __syncthreads();
    if(t<64){
      float sq=0.f, sk2=0.f;
      #pragma unroll
      for(int i=0;i<8;i++){ sq+=cq[i][t]; sk2+=ck[i][t]; }
      atomicAdd(&featd[h*128+t], (double)sq);
      atomicAdd(&featd[h*128+64+t], (double)sk2);
      float mk = sk2*(1.f/512.f);
      mkS[t]=mk;
      float s = wred64(mk);
      if(t==0){ smk[hq]=s; smkS=s; }
    }
    __syncthreads();
    {
      int n = t;
      float smkv = smkS;
      const unsigned short* fr = fqb + (size_t)(q*512+n)*512 + h*64;
      const unsigned short* kr = fkb + (size_t)(q*512+n)*512 + h*64;
      float sq=0.f, ssq=0.f, dq=0.f, sks=0.f, ssk=0.f;
      #pragma unroll
      for(int j=0;j<8;j++){
        s16x8 vq = *(const s16x8*)(fr + j*8);
        s16x8 vk = *(const s16x8*)(kr + j*8);
        #pragma unroll
        for(int e=0;e<8;e++){
          float a = b2f((unsigned short)vq[e]);
          float c = b2f((unsigned short)vk[e]);
          sq += a; ssq += a*a; dq += a*mkS[j*8+e];
          sks += c; ssk += c*c;
        }
      }
      int idx = hq*512 + n;
      float nq = sqrtf(ssq);
      ri1[idx]  = 1.f/(nq+1e-6f);
      mq[idx]   = sq*(1.f/64.f);
      qdm[idx]  = dq;
      float nk = sqrtf(ssk);
      ri2[idx]  = 1.f/(nk+1e-6f);
      sk[idx]   = sks - smkv;
    }
    return;
  }
  {
    int bb = bx - 128; int hq = bb>>2, nc = bb&3;
    int h = hq>>4, q = hq&15; int n0 = nc*128;
    __shared__ float tile[128][65];
    #pragma unroll
    for(int i=0;i<2;i++){
      int c = t + i*512; int row = c>>3, k8 = c&7;
      s16x8 v = *(const s16x8*)(fvb + (size_t)(q*512 + n0 + row)*512 + h*64 + k8*8);
      #pragma unroll
      for(int j=0;j<8;j++) tile[row][k8*8+j] = b2f((unsigned short)v[j]);
    }
    __syncthreads();
    #pragma unroll
    for(int i=0;i<2;i++){
      int c = t + i*512; int d = c>>4, n8 = c&15;
      s16x8 o;
      #pragma unroll
      for(int j=0;j<8;j++){
        int p = n8*8+j;
        int pl = p & 31;
        int src = (p & ~31) | (16*(pl&1) + (pl>>1));
        o[j] = (short)f2h(tile[src][d]);
      }
      *(s16x8*)(fvT + (size_t)(hq*64 + d)*512 + n0 + n8*8) = o;
    }
  }
}

// ---------------- component sums pass (MFMA QK), 128 q-rows / 512 threads, XCD-swizzled ----------------
__global__ __launch_bounds__(512) void k_comp(const unsigned short* __restrict__ fqb,
    const unsigned short* __restrict__ fkb,
    const float* __restrict__ ri1,
    const float* __restrict__ mq, const float* __restrict__ qdm,
    const float* __restrict__ ri2,
    const float* __restrict__ skp,
    float* __restrict__ mxcg, float* __restrict__ mxvg, double* headsum){
  int bid = blockIdx.x;
  int bx = (bid&7)*64 + (bid>>3);          // XCD swizzle: 4 row-tiles of an hq share an XCD's L2
  int hq = bx>>2; int rt = bx&3;
  int h = hq>>4, q = hq&15; int n0 = rt*128;
  __shared__ __align__(16) unsigned short Qs[128*64];
  __shared__ __align__(16) unsigned short Ks[128*64];
  __shared__ float ri2f[512], skf[512];
  __shared__ float red[8][9];
  int t = threadIdx.x; int w = t>>6; int l = t&63; int g = l>>4, lc = l&15;
  for(int i=t; i<512; i+=512){
    ri2f[i]=ri2[hq*NS+i]; skf[i]=skp[hq*NS+i];
  }
  #pragma unroll
  for(int i=0;i<2;i++){
    int c = t + i*512; int row = c>>3, k8 = c&7;
    s16x8 v = *(const s16x8*)(fqb + (size_t)(q*512 + n0 + row)*512 + h*64 + k8*8);
    *(s16x8*)((char*)Qs + row*128 + ((k8*16) ^ ((row&7)<<4))) = v;
  }
  float ri1r[4], mqr[4], qdmr[4];
  #pragma unroll
  for(int r=0;r<4;r++){
    int n = hq*NS + n0 + w*16 + g*4 + r;
    ri1r[r]=ri1[n]; mqr[r]=mq[n]; qdmr[r]=qdm[n];
  }
  __syncthreads();
  bf16x8 aq[2];
  #pragma unroll
  for(int ks=0;ks<2;ks++){
    int row = 16*w + lc;
    aq[ks] = *(const bf16x8*)((const char*)Qs + row*128 + (((ks*4+g)*16) ^ ((row&7)<<4)));
  }
  float p1=0,p3=0,p4=0;
  float rm_m[4]={0,0,0,0}, rm_c[4]={0,0,0,0}, rm_v[4]={0,0,0,0};
  float mxc[4]={-1e30f,-1e30f,-1e30f,-1e30f}, mxv[4]={-1e30f,-1e30f,-1e30f,-1e30f};
  for(int mc=0; mc<4; mc++){
    __syncthreads();
    #pragma unroll
    for(int i=0;i<2;i++){
      int c = t + i*512; int row = c>>3, k8 = c&7;
      s16x8 v = *(const s16x8*)(fkb + (size_t)(q*512 + mc*128 + row)*512 + h*64 + k8*8);
      *(s16x8*)((char*)Ks + row*128 + ((k8*16) ^ ((row&7)<<4))) = v;
    }
    __syncthreads();
    #pragma unroll 2
    for(int mt=0; mt<8; mt++){
      f32x4 dacc = (f32x4){0.f,0.f,0.f,0.f};
      #pragma unroll
      for(int ks=0;ks<2;ks++){
        int row = mt*16 + lc;
        bf16x8 bk = *(const bf16x8*)((const char*)Ks + row*128 + (((ks*4+g)*16) ^ ((row&7)<<4)));
        dacc = mfma16(aq[ks], bk, dacc);
      }
      int m = mc*128 + mt*16 + lc;
      float r2 = ri2f[m], sc = skf[m];
      #pragma unroll
      for(int r=0;r<4;r++){
        float dv = dacc[r];
        float cosv = fminf(fmaxf(dv*ri1r[r]*r2, -0.9f), 0.9f);
        float inner = (dv - qdmr[r]) - mqr[r]*sc;
        float marg = fmaxf(0.01f - cosv, 0.f);
        p1 += cosv*cosv; p3 += inner*inner; p4 += cosv*inner;
        rm_m[r]+=marg; rm_c[r]+=cosv; rm_v[r]+=inner;
        mxc[r]=fmaxf(mxc[r],cosv); mxv[r]=fmaxf(mxv[r],inner);
      }
    }
  }
  float p0 = rm_c[0]+rm_c[1]+rm_c[2]+rm_c[3];
  float p2 = rm_v[0]+rm_v[1]+rm_v[2]+rm_v[3];
  #pragma unroll
  for(int off=1; off<16; off<<=1){
    #pragma unroll
    for(int r=0;r<4;r++){
      rm_m[r]+=__shfl_xor(rm_m[r],off,64);
      rm_c[r]+=__shfl_xor(rm_c[r],off,64);
      rm_v[r]+=__shfl_xor(rm_v[r],off,64);
      mxc[r]=fmaxf(mxc[r],__shfl_xor(mxc[r],off,64));
      mxv[r]=fmaxf(mxv[r],__shfl_xor(mxv[r],off,64));
    }
  }
  float q0=0,q1=0,q2=0,q3=0;
  if(lc==0){
    #pragma unroll
    for(int r=0;r<4;r++){
      float vmv = rm_m[r]*(1.f/512.f);
      q0+=vmv; q1+=vmv*vmv; q2+=vmv*rm_c[r]; q3+=vmv*rm_v[r];
      int n = n0 + w*16 + g*4 + r;
      mxcg[hq*NS+n]=mxc[r]; mxvg[hq*NS+n]=mxv[r];
    }
  }
  float all9[9] = {p0,p1,p2,p3,p4,q0,q1,q2,q3};
  #pragma unroll
  for(int j=0;j<9;j++){
    float vv = wred64(all9[j]);
    if(l==0) red[w][j]=vv;
  }
  __syncthreads();
  if(t<9){
    double s = 0.0;
    #pragma unroll
    for(int i=0;i<8;i++) s += (double)red[i][t];
    atomicAdd(&headsum[h*9+t], s);
  }
}

// ---------------- finalize (512 threads, all heads parallel) ----------------
__global__ __launch_bounds__(512) void k_finalize(const double* headsum, const double* featd,
    const float* __restrict__ w1, const float* __restrict__ b1,
    const float* __restrict__ lng, const float* __restrict__ lnb,
    const float* __restrict__ w2, const float* __restrict__ b2,
    const float* __restrict__ w3, const float* __restrict__ b3,
    const float* __restrict__ wtemp, float* coef){
  __shared__ float fS[1024];
  __shared__ float x1[1024];
  __shared__ float x2[512];
  __shared__ float oS[8][3], whS[8][3];
  int t = threadIdx.x;
  fS[t]     = (float)(featd[t]     * (1.0/8192.0));
  fS[t+512] = (float)(featd[t+512] * (1.0/8192.0));
  __syncthreads();
  int hh = t>>6, j = t&63;
  {
    float a0 = b1[j], a1 = b1[j+64];
    #pragma unroll 8
    for(int i=0;i<128;i++){
      float f = fS[hh*128+i];
      a0 += f*w1[(size_t)i*128 + j];
      a1 += f*w1[(size_t)i*128 + j + 64];
    }
    float s = a0+a1, ss = a0*a0+a1*a1;
    s = wred64(s); ss = wred64(ss);
    float mu = s*(1.f/128.f), var = ss*(1.f/128.f)-mu*mu;
    float rstd = rsqrtf(var+1e-5f);
    x1[hh*128+j]    = fmaxf((a0-mu)*rstd*lng[j]+lnb[j], 0.f);
    x1[hh*128+j+64] = fmaxf((a1-mu)*rstd*lng[j+64]+lnb[j+64], 0.f);
  }
  __syncthreads();
  {
    float s2 = b2[j];
    #pragma unroll 8
    for(int i=0;i<128;i++) s2 += x1[hh*128+i]*w2[(size_t)i*64+j];
    x2[hh*64+j] = fmaxf(s2, 0.f);
  }
  __syncthreads();
  if(t < 24){
    int h3 = t/3, j3 = t-h3*3;
    float s3=0.f;
    #pragma unroll 8
    for(int i=0;i<64;i++) s3 += x2[h3*64+i]*w3[i*3+j3];
    oS[h3][j3] = s3 + b3[j3];
  }
  __syncthreads();
  if(t < 8){
    float o0=oS[t][0], o1=oS[t][1], o2=oS[t][2];
    float mx=fmaxf(o0,fmaxf(o1,o2));
    float e0=expf(o0-mx), e1=expf(o1-mx), e2=expf(o2-mx), se=e0+e1+e2;
    float l0=e0/se, l1=e1/se, l2=e2/se;
    float wt=fminf(fmaxf(wtemp[0],0.1f),2.0f);
    l0/=wt; l1/=wt; l2/=wt;
    mx=fmaxf(l0,fmaxf(l1,l2));
    e0=expf(l0-mx); e1=expf(l1-mx); e2=expf(l2-mx); se=e0+e1+e2;
    float u0=fminf(fmaxf(e0/se,0.05f),0.8f);
    float u1=fminf(fmaxf(e1/se,0.05f),0.8f);
    float u2=fminf(fmaxf(e2/se,0.05f),0.8f);
    float su=u0+u1+u2;
    whS[t][0]=u0/su; whS[t][1]=u1/su; whS[t][2]=u2/su;
  }
  __syncthreads();
  if(t==0){
    const double N = 33554432.0;
    const double CS2d = (double)CS2;
    double gs[9];
    for(int jj=0;jj<9;jj++){ double s=0; for(int h2=0;h2<8;h2++) s+=headsum[h2*9+jj]; gs[jj]=s; }
    auto sd = [&](double s, double ss)->double{
      double vv=(ss - s*s/N)/(N-1.0); return vv>0.0 ? sqrt(vv) : 0.0;
    };
    double std_cos = sd(gs[0],gs[1]);
    double std_cov = sd(CS2d*gs[2], CS2d*CS2d*gs[3]);
    double std_vm  = sd(512.0*gs[5], 512.0*gs[6]);
    double sdot=0.0, sdot2=0.0;
    double Af[8], Bf[8];
    for(int h2=0;h2<8;h2++){
      const double* hs = headsum + h2*9;
      double A = (double)whS[h2][0]/(std_cos+1e-6);
      double Bi = (double)whS[h2][1]/(std_cov+1e-6)*0.5*CS2d;
      double C = (double)whS[h2][2]/(std_vm +1e-6)*0.5;
      sdot  += A*hs[0] + Bi*hs[2] + C*512.0*hs[5];
      sdot2 += A*A*hs[1] + Bi*Bi*hs[3] + C*C*512.0*hs[6]
             + 2.0*A*Bi*hs[4] + 2.0*A*C*hs[7] + 2.0*Bi*C*hs[8];
      Af[h2]=A; Bf[h2]=Bi;
    }
    double dstd = sd(sdot, sdot2);
    double temp = dstd < 1e-4 ? 0.1 : (dstd < 0.01 ? 0.3 : 0.5 + dstd);
    temp = fmin(fmax(temp, 0.1), 3.0);
    for(int h2=0;h2<8;h2++){
      coef[h2]   = (float)(Af[h2]/temp*LOG2E);
      coef[8+h2] = (float)(Bf[h2]/temp*LOG2E);
    }
    coef[16] = (float)temp;
  }
}

// ---------------- flash softmax + PV (fp16 P/V), 128 q-rows / 512 threads, XCD-swizzled ----------------
__global__ __launch_bounds__(512) void k_flash(const unsigned short* __restrict__ fqb,
    const unsigned short* __restrict__ fkb, const unsigned short* __restrict__ fvT,
    const float* __restrict__ ri1, const float* __restrict__ mq,
    const float* __restrict__ qdm, const float* __restrict__ ri2,
    const float* __restrict__ skp,
    const float* __restrict__ mxcg, const float* __restrict__ mxvg,
    const float* __restrict__ coef,
    unsigned short* __restrict__ ohh){
  int bid = blockIdx.x;
  int bx = (bid&7)*64 + (bid>>3);          // XCD swizzle
  int hq = bx>>2; int rt = bx&3;
  int h = hq>>4, q = hq&15; int n0 = rt*128;
  __shared__ __align__(16) unsigned short Qs[128*64];  // reused as P after aq extraction
  __shared__ __align__(16) unsigned short Ks[128*64];
  __shared__ __align__(16) unsigned short Vt[64*128];
  __shared__ float ri2f[512], skf[512];
  int t = threadIdx.x; int w = t>>6; int l = t&63; int g = l>>4, lc = l&15;
  for(int i=t; i<512; i+=512){ ri2f[i]=ri2[hq*NS+i]; skf[i]=skp[hq*NS+i]; }
  #pragma unroll
  for(int i=0;i<2;i++){
    int c = t + i*512; int row = c>>3, k8 = c&7;
    s16x8 v = *(const s16x8*)(fqb + (size_t)(q*512 + n0 + row)*512 + h*64 + k8*8);
    *(s16x8*)((char*)Qs + row*128 + ((k8*16) ^ ((row&7)<<4))) = v;
  }
  float Ah = coef[h], Bh = coef[8+h];
  float loA = -0.9f*Ah, hiA = 0.9f*Ah;
  float ri1A[4], R1[4], R2[4];
  #pragma unroll
  for(int r=0;r<4;r++){
    int n = hq*NS + n0 + w*16 + g*4 + r;
    float Mr = Ah*mxcg[n] + Bh*mxvg[n];
    ri1A[r] = ri1[n]*Ah;
    R1[r] = fmaf(Bh, qdm[n], Mr);
    R2[r] = Bh*mq[n];
  }
  __syncthreads();
  bf16x8 aq[2];
  #pragma unroll
  for(int ks=0;ks<2;ks++){
    int row = 16*w + lc;
    aq[ks] = *(const bf16x8*)((const char*)Qs + row*128 + (((ks*4+g)*16) ^ ((row&7)<<4)));
  }
  f32x4 acc[4];
  #pragma unroll
  for(int dt=0;dt<4;dt++) acc[dt] = (f32x4){0.f,0.f,0.f,0.f};
  float lsum[4]={0.f,0.f,0.f,0.f};
  unsigned short* Pw = Qs + w*640;
  unsigned* Pu = (unsigned*)Pw;
  for(int mc=0; mc<4; mc++){
    __syncthreads();
    #pragma unroll
    for(int i=0;i<2;i++){
      int c = t + i*512; int row = c>>3, k8 = c&7;
      s16x8 v = *(const s16x8*)(fkb + (size_t)(q*512 + mc*128 + row)*512 + h*64 + k8*8);
      *(s16x8*)((char*)Ks + row*128 + ((k8*16) ^ ((row&7)<<4))) = v;
    }
    #pragma unroll
    for(int i=0;i<2;i++){
      int c = t + i*512; int d = c>>4, m8 = c&15;
      s16x8 v = *(const s16x8*)(fvT + (size_t)(hq*64 + d)*512 + mc*128 + m8*8);
      *(s16x8*)((char*)Vt + d*256 + ((m8*16) ^ ((d&7)<<4))) = v;
    }
    __syncthreads();
    #pragma unroll 1
    for(int mt2=0; mt2<4; mt2++){
      f32x4 d0 = (f32x4){0.f,0.f,0.f,0.f};
      f32x4 d1 = (f32x4){0.f,0.f,0.f,0.f};
      #pragma unroll
      for(int ks=0;ks<2;ks++){
        int row0 = (mt2*2)*16 + lc;
        bf16x8 bk0 = *(const bf16x8*)((const char*)Ks + row0*128 + (((ks*4+g)*16) ^ ((row0&7)<<4)));
        d0 = mfma16(aq[ks], bk0, d0);
        int row1 = (mt2*2+1)*16 + lc;
        bf16x8 bk1 = *(const bf16x8*)((const char*)Ks + row1*128 + (((ks*4+g)*16) ^ ((row1&7)<<4)));
        d1 = mfma16(aq[ks], bk1, d1);
      }
      int m0 = mc*128 + mt2*32 + lc;
      float r20 = ri2f[m0],    sc0 = skf[m0];
      float r21 = ri2f[m0+16], sc1 = skf[m0+16];
      #pragma unroll
      for(int r=0;r<4;r++){
        float dv0 = d0[r], dv1 = d1[r];
        float cl0 = fminf(fmaxf(dv0*ri1A[r]*r20, loA), hiA);
        float cl1 = fminf(fmaxf(dv1*ri1A[r]*r21, loA), hiA);
        float e0 = fmaf(-R2[r], sc0, fmaf(Bh, dv0, -R1[r]));
        float e1 = fmaf(-R2[r], sc1, fmaf(Bh, dv1, -R1[r]));
        float pe0 = __builtin_amdgcn_exp2f(cl0 + e0);
        float pe1 = __builtin_amdgcn_exp2f(cl1 + e1);
        lsum[r] += pe0 + pe1;
        auto ph = __builtin_amdgcn_cvt_pkrtz(pe0, pe1);
        unsigned pk; __builtin_memcpy(&pk, &ph, 4);
        Pu[(g*4+r)*20 + lc] = pk;
      }
      asm volatile("s_waitcnt lgkmcnt(0)" ::: "memory");
      f16x8 ap = *(const f16x8*)((const char*)Pw + lc*80 + g*16);
      #pragma unroll
      for(int dt=0;dt<4;dt++){
        int drow = dt*16 + lc;
        f16x8 bv = *(const f16x8*)((const char*)Vt + drow*256 + (((mt2*4+g)*16) ^ ((drow&7)<<4)));
        acc[dt] = mfma16h(ap, bv, acc[dt]);
      }
    }
  }
  #pragma unroll
  for(int off=1; off<16; off<<=1){
    #pragma unroll
    for(int r=0;r<4;r++) lsum[r] += __shfl_xor(lsum[r], off, 64);
  }
  #pragma unroll
  for(int r=0;r<4;r++){
    float inv = 1.f/lsum[r];
    int n = n0 + w*16 + g*4 + r;
    #pragma unroll
    for(int dt=0;dt<4;dt++){
      size_t idx = (size_t)(q*512 + n)*512 + h*64 + dt*16 + lc;
      ohh[idx] = f2h(acc[dt][r]*inv);
    }
  }
}

// ---------------- output GEMM: fp16 A x fp16 (Bh+Bl) 2-term MFMA + bias, XCD-chunked ----------------
__global__ __launch_bounds__(256) void k_gout2(const unsigned short* __restrict__ Ap,
    const unsigned short* __restrict__ Bhp, const unsigned short* __restrict__ Blp,
    const float* __restrict__ bias, float* __restrict__ Cout){
  __shared__ __align__(16) unsigned short As[128*64];
  __shared__ __align__(16) unsigned short BsH[128*64];
  __shared__ __align__(16) unsigned short BsL[128*64];
  int t = threadIdx.x; int w = t>>6; int l = t&63; int g = l>>4, lc = l&15;
  int bid = blockIdx.x;
  int work = (bid&7)*32 + (bid>>3);        // 256 blocks, 32 per XCD chunk
  int Rb = (work>>2)*128, cb = (work&3)*128;
  int wr = (w>>1)*64, wc = (w&1)*64;
  f32x4 acc[4][4];
  #pragma unroll
  for(int i=0;i<4;i++)
    #pragma unroll
    for(int j=0;j<4;j++) acc[i][j] = (f32x4){0.f,0.f,0.f,0.f};
  for(int k0=0; k0<512; k0+=64){
    __syncthreads();
    #pragma unroll
    for(int i=0;i<4;i++){
      int c = t + i*256; int row = c>>3, k8 = c&7;
      int sw = (k8*16) ^ ((row&7)<<4);
      *(s16x8*)((char*)As  + row*128 + sw) = *(const s16x8*)(Ap  + (size_t)(Rb+row)*512 + k0 + k8*8);
      *(s16x8*)((char*)BsH + row*128 + sw) = *(const s16x8*)(Bhp + (size_t)(cb+row)*512 + k0 + k8*8);
      *(s16x8*)((char*)BsL + row*128 + sw) = *(const s16x8*)(Blp + (size_t)(cb+row)*512 + k0 + k8*8);
    }
    __syncthreads();
    #pragma unroll
    for(int ks=0; ks<2; ks++){
      f16x8 ar[4], brh[4], brl[4];
      #pragma unroll
      for(int rt=0; rt<4; rt++){
        int row = wr + rt*16 + lc;
        ar[rt] = *(const f16x8*)((const char*)As + row*128 + (((ks*4+g)*16) ^ ((row&7)<<4)));
      }
      #pragma unroll
      for(int ct=0; ct<4; ct++){
        int row = wc + ct*16 + lc;
        int off = row*128 + (((ks*4+g)*16) ^ ((row&7)<<4));
        brh[ct] = *(const f16x8*)((const char*)BsH + off);
        brl[ct] = *(const f16x8*)((const char*)BsL + off);
      }
      #pragma unroll
      for(int rt=0; rt<4; rt++)
        #pragma unroll
        for(int ct=0; ct<4; ct++){
          acc[rt][ct] = mfma16h(ar[rt], brh[ct], acc[rt][ct]);
          acc[rt][ct] = mfma16h(ar[rt], brl[ct], acc[rt][ct]);
        }
    }
  }
  #pragma unroll
  for(int rt=0; rt<4; rt++){
    #pragma unroll
    for(int r=0; r<4; r++){
      int R = Rb + wr + rt*16 + g*4 + r;
      #pragma unroll
      for(int ct=0; ct<4; ct++){
        int c = cb + wc + ct*16 + lc;
        Cout[(size_t)R*512 + c] = acc[rt][ct][r] + bias[c];
      }
    }
  }
}

extern "C" void kernel_launch(void* const* d_in, const int* in_sizes, int n_in,
                              void* d_out, int out_size, void* d_ws, size_t ws_size,
                              hipStream_t stream){
  const float* q    = (const float*)d_in[0];
  const float* k    = (const float*)d_in[1];
  const float* v    = (const float*)d_in[2];
  const float* ln1g = (const float*)d_in[3];
  const float* ln1b = (const float*)d_in[4];
  const float* Win  = (const float*)d_in[5];
  const float* w1   = (const float*)d_in[6];
  const float* b1   = (const float*)d_in[7];
  const float* lng  = (const float*)d_in[8];
  const float* lnb  = (const float*)d_in[9];
  const float* w2   = (const float*)d_in[10];
  const float* b2   = (const float*)d_in[11];
  const float* w3   = (const float*)d_in[12];
  const float* b3   = (const float*)d_in[13];
  const float* wtemp= (const float*)d_in[14];
  const float* Wout = (const float*)d_in[15];
  const float* bout = (const float*)d_in[16];

  float* w = (float*)d_ws;
  unsigned short* xnb = (unsigned short*)(w + OFF_XNB);
  unsigned short* fqb = (unsigned short*)(w + OFF_FQB);
  unsigned short* fkb = (unsigned short*)(w + OFF_FKB);
  unsigned short* fvb = (unsigned short*)(w + OFF_FVB);
  unsigned short* fvT = (unsigned short*)(w + OFF_FVT);
  unsigned short* wtb = (unsigned short*)(w + OFF_WT);
  unsigned short* woh = (unsigned short*)(w + OFF_WOH);
  unsigned short* wol = (unsigned short*)(w + OFF_WOL);
  unsigned short* ohh = (unsigned short*)(w + OFF_OHH);
  float* ri1  = w + OFF_ARR + 0*65536;
  float* mq_  = w + OFF_ARR + 2*65536;
  float* qdm  = w + OFF_ARR + 3*65536;
  float* ri2  = w + OFF_ARR + 4*65536;
  float* sk_  = w + OFF_ARR + 6*65536;
  float* mxc  = w + OFF_ARR + 7*65536;
  float* mxv  = w + OFF_ARR + 8*65536;
  float* smk_ = w + OFF_SMK;
  float* coef = w + OFF_COEF;
  double* dbl = (double*)(w + OFF_DBL);
  double* headsum = dbl;
  double* featd   = dbl + 72;

  k_pre<<<6272, 256, 0, stream>>>(q, k, v, ln1g, ln1b, Win, Wout, xnb, wtb, woh, wol, dbl);
  k_mm1<<<768, 256, 0, stream>>>(xnb, wtb, fqb, fkb, fvb);
  k_mid<<<640, 512, 0, stream>>>(fqb, fkb, fvb, smk_, featd, ri1, mq_, qdm, ri2, sk_, fvT);
  k_comp<<<512, 512, 0, stream>>>(fqb, fkb, ri1, mq_, qdm, ri2, sk_, mxc, mxv, headsum);
  k_finalize<<<1, 512, 0, stream>>>(headsum, featd, w1, b1, lng, lnb, w2, b2, w3, b3, wtemp, coef);
  k_flash<<<512, 512, 0, stream>>>(fqb, fkb, fvT, ri1, mq_, qdm, ri2, sk_, mxc, mxv, coef, ohh);
  k_gout2<<<256, 256, 0, stream>>>(ohh, woh, wol, bout, (float*)d_out);
}